// Round 1
// 356.129 us; speedup vs baseline: 1.3707x; 1.3707x over previous
//
#include <hip/hip_runtime.h>

// LSA_2147483648500: x[4,2048,1024](fp32) -> QKV proj -> 16-head attention
// (diag masked) -> out proj + bias. Internal bf16 MFMA; runtime dtype-detect.
//
// R9: the 162us/902MB-write dispatch is gemm_bt<1> (LDS_Block_Size=16384
// matches MODE 1; MODE 0 carries lC and would report 33280). R8 fixed the
// wrong epilogue. MODE 1's 64 scattered per-lane dword stores (4 rows x
// 64B chunks per instruction) cause ~27x partial-line write amplification.
// Now MODE 1 stages the fp32 tile (+bias) in LDS (two 64-row halves,
// padded stride 132) and stores cooperatively: 32 lanes x float4 = one
// full 512B row per instruction, every 128B line written once, fully.
// K-loop, MODE 0, attention, transposes frozen from R8.

using u16 = unsigned short;
typedef short short8 __attribute__((ext_vector_type(8)));
typedef float floatx4 __attribute__((ext_vector_type(4)));

#define B_ 4
#define N_ 2048
#define H_ 16
#define DH_ 64
#define D_ 1024
#define INNER_ 1024
#define M_ (B_ * N_)   // 8192

__device__ __forceinline__ float bf2f(u16 h) {
    union { unsigned u; float f; } c; c.u = ((unsigned)h) << 16; return c.f;
}
__device__ __forceinline__ u16 f2bf(float f) {
    union { float f; unsigned u; } c; c.f = f;
    unsigned u = c.u + 0x7fffu + ((c.u >> 16) & 1u);
    return (u16)(u >> 16);
}
// pack two non-negative floats to bf16x2 (round-half-up)
__device__ __forceinline__ unsigned pack2(float a, float b) {
    union { float f; unsigned u; } ca, cb; ca.f = a; cb.f = b;
    return ((cb.u + 0x8000u) & 0xFFFF0000u) | ((ca.u + 0x8000u) >> 16);
}
__device__ __forceinline__ float fast_exp2(float x) {
#if defined(__has_builtin) && __has_builtin(__builtin_amdgcn_exp2f)
    return __builtin_amdgcn_exp2f(x);
#else
    return __expf(x * 0.69314718056f);
#endif
}
__device__ __forceinline__ void gl2lds16(const u16* g, u16* l) {
    __builtin_amdgcn_global_load_lds(
        (const __attribute__((address_space(1))) void*)g,
        (__attribute__((address_space(3))) void*)l, 16, 0, 0);
}

// -------- dtype detect: flag=1 if x's u16s look like bf16, else 0 ----------
__global__ void detect_dtype(const u16* __restrict__ x, int* __restrict__ flag) {
    __shared__ int cnt;
    if (threadIdx.x == 0) cnt = 0;
    __syncthreads();
    int c = 0;
    for (int i = threadIdx.x; i < 4096; i += 256) {
        int e = (x[i] >> 7) & 0xFF;
        if (e >= 107 && e <= 147) c++;
    }
    atomicAdd(&cnt, c);
    __syncthreads();
    if (threadIdx.x == 0) flag[0] = (cnt >= 3584) ? 1 : 0;
}

// -------- convert x (fp32 or bf16) -> bf16 ---------------------------------
__global__ __launch_bounds__(256) void convert_x(
    const void* __restrict__ in, u16* __restrict__ out, int n,
    const int* __restrict__ flag) {
    int f = flag[0];
    int i0 = (blockIdx.x * 256 + threadIdx.x) * 8;
    if (f) {
        const u16* p = (const u16*)in;
        for (int i = 0; i < 8; i++) out[i0 + i] = p[i0 + i];
    } else {
        const float* p = (const float*)in;
        for (int i = 0; i < 8; i++) out[i0 + i] = f2bf(p[i0 + i]);
    }
}

// -------- prep: bias -> fp32[1024], temperature -> fp32[1] -----------------
__global__ void prep_misc(const void* __restrict__ bias_in,
                          const void* __restrict__ temp_in,
                          float* __restrict__ bias_f, float* __restrict__ temp_f,
                          const int* __restrict__ flag) {
    int f = flag[0];
    for (int i = threadIdx.x; i < 1024; i += 256)
        bias_f[i] = f ? bf2f(((const u16*)bias_in)[i]) : ((const float*)bias_in)[i];
    if (threadIdx.x == 0)
        temp_f[0] = f ? bf2f(((const u16*)temp_in)[0]) : ((const float*)temp_in)[0];
}

// -------- transpose+convert: out[c][r] = bf16(in[r][c]) --------------------
__global__ __launch_bounds__(256) void transpose_cvt(
    const void* __restrict__ in, u16* __restrict__ out, int R, int C,
    const int* __restrict__ flag) {
    __shared__ u16 t[32][33];
    int f = flag[0];
    int tx = threadIdx.x & 31, ty = threadIdx.x >> 5;
    int c0 = blockIdx.x * 32, r0 = blockIdx.y * 32;
    for (int i = 0; i < 4; i++) {
        long idx = (long)(r0 + ty + i * 8) * C + c0 + tx;
        t[ty + i * 8][tx] = f ? ((const u16*)in)[idx] : f2bf(((const float*)in)[idx]);
    }
    __syncthreads();
    for (int i = 0; i < 4; i++)
        out[(long)(c0 + ty + i * 8) * R + r0 + tx] = t[tx][ty + i * 8];
}

// -------- transpose v: per-bh [N][64] -> [64][N], bf16 ----------------------
__global__ __launch_bounds__(256) void transpose_v(
    const u16* __restrict__ in, u16* __restrict__ out) {
    __shared__ u16 t[32][33];
    const int bh = blockIdx.z;
    const u16* src = in + (long)bh * N_ * DH_;
    u16* dst = out + (long)bh * DH_ * N_;
    int tx = threadIdx.x & 31, ty = threadIdx.x >> 5;
    int r0 = blockIdx.y * 32;   // n rows
    int c0 = blockIdx.x * 32;   // dh cols
    for (int i = 0; i < 4; i++)
        t[ty + i * 8][tx] = src[(long)(r0 + ty + i * 8) * DH_ + c0 + tx];
    __syncthreads();
    for (int i = 0; i < 4; i++)
        dst[(long)(c0 + ty + i * 8) * N_ + r0 + tx] = t[tx][ty + i * 8];
}

// ---------------- GEMM: C[M,N] = A[M,K] * Bt[N,K]^T, bf16 MFMA --------------
// 128x128 tile, BK=32, 4 waves 2x2, swizzled LDS via source-permuted
// global_load_lds. MODE 0: LDS-staged coalesced scatter to q (pre-scaled),
// k, v — all [BH][N][DH]. MODE 1: +bias, LDS-staged coalesced store
// (full-line float4 / short8 per lane) to outv.
template <int MODE>
__global__ __launch_bounds__(256) void gemm_bt(
    const u16* __restrict__ A, const u16* __restrict__ Bt,
    int M, int N, int K,
    u16* __restrict__ out0, u16* __restrict__ out1, u16* __restrict__ out2,
    void* __restrict__ outv, const float* __restrict__ bias,
    const int* __restrict__ flag, const float* __restrict__ temp_f) {
    __shared__ __align__(16) u16 lA[128 * 32];
    __shared__ __align__(16) u16 lB[128 * 32];
    const int tid = threadIdx.x;
    const int lane = tid & 63;
    const int w = tid >> 6;
    const int wr = w >> 1, wc = w & 1;
    const int qd = lane >> 4, qm = lane & 15;
    const long m0 = (long)blockIdx.x * 128;
    const long n0 = (long)blockIdx.y * 128;

    floatx4 acc[4][4];
    for (int i = 0; i < 4; i++)
        for (int j = 0; j < 4; j++) acc[i][j] = (floatx4){0.f, 0.f, 0.f, 0.f};

    const int arow = lane >> 2;
    const int acol = ((lane & 3) ^ ((lane >> 3) & 3)) * 8;
    const int swz = (qm >> 1) & 3;

    for (int k0 = 0; k0 < K; k0 += 32) {
        for (int i = 0; i < 2; i++) {
            int c = w + i * 4;
            gl2lds16(A + (m0 + c * 16 + arow) * K + k0 + acol, lA + c * 512);
            gl2lds16(Bt + (n0 + c * 16 + arow) * K + k0 + acol, lB + c * 512);
        }
        __syncthreads();
        short8 af[4], bfr[4];
        for (int mt = 0; mt < 4; mt++)
            af[mt] = *(const short8*)&lA[(wr * 64 + mt * 16 + qm) * 32 + (qd ^ swz) * 8];
        for (int nt = 0; nt < 4; nt++)
            bfr[nt] = *(const short8*)&lB[(wc * 64 + nt * 16 + qm) * 32 + (qd ^ swz) * 8];
        for (int mt = 0; mt < 4; mt++)
            for (int nt = 0; nt < 4; nt++)
                acc[mt][nt] = __builtin_amdgcn_mfma_f32_16x16x32_bf16(
                    af[mt], bfr[nt], acc[mt][nt], 0, 0, 0);
        __syncthreads();
    }

    if (MODE == 0) {
        // LDS-staged epilogue: two 64-row halves; each 128B output line is
        // written once, fully, by a single dwordx4-per-lane instruction.
        const float qscale = __expf(temp_f[0]) * 1.44269504089f;
        __shared__ __align__(16) u16 lC[64 * 132];
        for (int half = 0; half < 2; half++) {
            __syncthreads();
            if (wr == half) {
                for (int nt = 0; nt < 4; nt++) {
                    long ng = n0 + wc * 64 + nt * 16 + qm;
                    float sc = ((ng >> 10) == 0) ? qscale : 1.0f;
                    for (int mt = 0; mt < 4; mt++)
                        for (int r = 0; r < 4; r++)
                            lC[(mt * 16 + qd * 4 + r) * 132 + wc * 64 + nt * 16 + qm] =
                                f2bf(acc[mt][nt][r] * sc);
                }
            }
            __syncthreads();
            for (int i = 0; i < 4; i++) {
                int row = (tid >> 4) + i * 16;       // 0..63
                int c = (tid & 15) * 8;              // col, 8-aligned
                long m = m0 + half * 64 + row;
                long ngc = n0 + c;
                int part = (int)(ngc >> 10);
                int rem = (int)(ngc & 1023);
                int hh = rem >> 6, dh = rem & 63;
                long bb = m >> 11, n = m & 2047;
                long idx = ((bb * H_ + hh) * N_ + n) * DH_ + dh;
                short8 vv = *(const short8*)&lC[row * 132 + c];
                u16* dst = (part == 0) ? out0 : (part == 1) ? out1 : out2;
                *(short8*)&dst[idx] = vv;
            }
        }
    } else {
        // LDS-staged fp32 epilogue, same structure as MODE 0: stage
        // acc+bias into lCf (64-row half, padded stride 132 dwords), then
        // cooperative full-line stores: 32 lanes x float4 = one 512B row
        // per instruction (f=0), or 16 lanes x short8 per 256B row (f=1).
        const int f = flag[0];
        __shared__ __align__(16) float lCf[64 * 132];
        for (int half = 0; half < 2; half++) {
            __syncthreads();
            if (wr == half) {
                for (int nt = 0; nt < 4; nt++) {
                    long ng = n0 + wc * 64 + nt * 16 + qm;
                    float bv = bias[ng];
                    for (int mt = 0; mt < 4; mt++)
                        for (int r = 0; r < 4; r++)
                            lCf[(mt * 16 + qd * 4 + r) * 132 + wc * 64 + nt * 16 + qm] =
                                acc[mt][nt][r] + bv;
                }
            }
            __syncthreads();
            if (f) {
                for (int i = 0; i < 4; i++) {
                    int row = (tid >> 4) + i * 16;   // 0..63
                    int c = (tid & 15) * 8;          // col, 8-aligned
                    long m = m0 + half * 64 + row;
                    u16 tmp[8];
                    for (int j = 0; j < 8; j++) tmp[j] = f2bf(lCf[row * 132 + c + j]);
                    *(short8*)&((u16*)outv)[m * N + n0 + c] = *(const short8*)tmp;
                }
            } else {
                for (int i = 0; i < 8; i++) {
                    int row = (tid >> 5) + i * 8;    // 0..63
                    int c = (tid & 31) * 4;          // col, 4-aligned fp32
                    long m = m0 + half * 64 + row;
                    floatx4 vv = *(const floatx4*)&lCf[row * 132 + c];
                    *(floatx4*)&((float*)outv)[m * N + n0 + c] = vv;
                }
            }
        }
    }
}

// ---------------- flash attention (S^T + register transform) ---------------
// grid = (N/128, B*H). 256 thr = 4 waves; wave w owns q rows w*32..w*32+31.
// S^T = K*Q^T -> lane(qd,qm) holds P[qrow=qm+16mt][key=k0+kt*16+qd*4+r].
// PV A-frag assembled via pack2 + __shfl; no P LDS buffer.
__global__ __launch_bounds__(256) void attn_kernel(
    const u16* __restrict__ q_ws, const u16* __restrict__ k_ws,
    const u16* __restrict__ vt_ws, u16* __restrict__ out) {
    __shared__ __align__(16) u16 lK[64 * 64];
    __shared__ __align__(16) u16 lV[64 * 64];
    const int tid = threadIdx.x, lane = tid & 63, w = tid >> 6;
    const int qd = lane >> 4, qm = lane & 15;
    const int bh = blockIdx.y;
    const int q0 = blockIdx.x * 128;
    const int b = bh >> 4, h = bh & 15;

    const u16* Q = q_ws + (long)bh * N_ * DH_;
    const u16* Kp = k_ws + (long)bh * N_ * DH_;
    const u16* Vt = vt_ws + (long)bh * DH_ * N_;

    short8 qa[2][2];
    for (int mt = 0; mt < 2; mt++)
        for (int s = 0; s < 2; s++)
            qa[mt][s] = *(const short8*)
                &Q[(q0 + w * 32 + mt * 16 + qm) * DH_ + s * 32 + qd * 8];

    floatx4 accO[2][4];
    float lacc[2] = {0.f, 0.f};
    for (int mt = 0; mt < 2; mt++)
        for (int i = 0; i < 4; i++) accO[mt][i] = (floatx4){0.f, 0.f, 0.f, 0.f};

    const int rbase = q0 + w * 32;
    const int srow = lane >> 3;
    const int scol = ((lane & 7) ^ srow) * 8;
    const int csw = qm & 7;

    for (int k0 = 0; k0 < N_; k0 += 64) {
        for (int i = 0; i < 2; i++) {
            int c = w + i * 4;
            gl2lds16(Kp + (long)(k0 + c * 8 + srow) * DH_ + scol, lK + c * 512);
            gl2lds16(Vt + (long)(c * 8 + srow) * N_ + k0 + scol, lV + c * 512);
        }
        __syncthreads();

        // S^T = K Q^T : m = 64 keys (4 kt tiles), n = 32 qrows (2 mt tiles)
        floatx4 accS[4][2];
        for (int kt = 0; kt < 4; kt++)
            for (int mt = 0; mt < 2; mt++) accS[kt][mt] = (floatx4){0.f, 0.f, 0.f, 0.f};
        for (int s = 0; s < 2; s++)
            for (int kt = 0; kt < 4; kt++) {
                short8 kb = *(const short8*)
                    &lK[(kt * 16 + qm) * 64 + ((s * 4 + qd) ^ csw) * 8];
                for (int mt = 0; mt < 2; mt++)
                    accS[kt][mt] = __builtin_amdgcn_mfma_f32_16x16x32_bf16(
                        kb, qa[mt][s], accS[kt][mt], 0, 0, 0);
            }

        // p = exp2(S^T) (q pre-scaled by exp(temp)*log2e); diag zero;
        // per-lane row-sum (qrow = qm fixed per lane); pack r-pairs to bf16x2.
        const bool diag = ((unsigned)(rbase - k0) < 64u);
        unsigned pk[2][4][2];
        for (int mt = 0; mt < 2; mt++) {
            float rs = 0.f;
            for (int kt = 0; kt < 4; kt++) {
                float p0 = fast_exp2(accS[kt][mt][0]);
                float p1 = fast_exp2(accS[kt][mt][1]);
                float p2 = fast_exp2(accS[kt][mt][2]);
                float p3 = fast_exp2(accS[kt][mt][3]);
                if (diag) {
                    int kbase = k0 + kt * 16 + qd * 4;
                    int qrow = rbase + mt * 16 + qm;
                    if (kbase + 0 == qrow) p0 = 0.f;
                    if (kbase + 1 == qrow) p1 = 0.f;
                    if (kbase + 2 == qrow) p2 = 0.f;
                    if (kbase + 3 == qrow) p3 = 0.f;
                }
                rs += (p0 + p1) + (p2 + p3);
                pk[mt][kt][0] = pack2(p0, p1);
                pk[mt][kt][1] = pack2(p2, p3);
            }
            lacc[mt] += rs;
        }

        // O += P V : assemble A-frag P[qm+16mt][s*32+qd*8+j] via shfl.
        for (int s = 0; s < 2; s++) {
            short8 vb[4];
            for (int dt = 0; dt < 4; dt++)
                vb[dt] = *(const short8*)
                    &lV[(dt * 16 + qm) * 64 + ((s * 4 + qd) ^ csw) * 8];
            for (int mt = 0; mt < 2; mt++) {
                union { unsigned u[4]; short8 v; } pa;
                for (int t = 0; t < 4; t++) {
                    int src = ((qd & 1) * 2 + (t >> 1)) * 16 + qm;
                    unsigned lo = (unsigned)__shfl((int)pk[mt][s * 2][t & 1], src, 64);
                    unsigned hi = (unsigned)__shfl((int)pk[mt][s * 2 + 1][t & 1], src, 64);
                    pa.u[t] = (qd >> 1) ? hi : lo;
                }
                for (int dt = 0; dt < 4; dt++)
                    accO[mt][dt] = __builtin_amdgcn_mfma_f32_16x16x32_bf16(
                        pa.v, vb[dt], accO[mt][dt], 0, 0, 0);
            }
        }
        __syncthreads();
    }

    // l: reduce per-lane partials over qd lanes; normalize + store.
    for (int mt = 0; mt < 2; mt++) {
        float s = lacc[mt];
        s += __shfl_xor(s, 16, 64);
        s += __shfl_xor(s, 32, 64);
        float inv = 1.f / s;                       // for qrow = mt*16 + qm
        for (int r = 0; r < 4; r++) {
            float invr = __shfl(inv, qd * 4 + r, 64);  // qrow = mt*16+qd*4+r
            int row = rbase + mt * 16 + qd * 4 + r;
            for (int dt = 0; dt < 4; dt++)
                out[((long)(b * N_ + row)) * INNER_ + h * DH_ + dt * 16 + qm] =
                    f2bf(accO[mt][dt][r] * invr);
        }
    }
}

extern "C" void kernel_launch(void* const* d_in, const int* in_sizes, int n_in,
                              void* d_out, int out_size, void* d_ws, size_t ws_size,
                              hipStream_t stream) {
    const void* x    = d_in[0];
    const void* Wqkv = d_in[1];
    const void* Wout = d_in[2];
    const void* bout = d_in[3];
    const void* temp = d_in[4];

    char* base = (char*)d_ws;
    int*   flag    = (int*)base;
    float* temp_f  = (float*)(base + 16);
    float* bias_f  = (float*)(base + 32);
    u16* xb      = (u16*)(base + 8192);
    u16* Wqkv_t  = xb + (long)M_ * D_;
    u16* Wout_t  = Wqkv_t + 3072 * 1024;
    u16* q_ws    = Wout_t + 1024 * 1024;
    u16* k_ws    = q_ws + (long)B_ * H_ * N_ * DH_;
    u16* vt_ws   = k_ws + (long)B_ * H_ * N_ * DH_;
    u16* attn_out = vt_ws + (long)B_ * H_ * N_ * DH_;
    u16* v_nat   = attn_out;  // alias: dead until attn_kernel writes it

    dim3 blk(256);
    detect_dtype<<<1, blk, 0, stream>>>((const u16*)x, flag);
    convert_x<<<dim3(M_ * D_ / (256 * 8)), blk, 0, stream>>>(x, xb, M_ * D_, flag);
    prep_misc<<<1, blk, 0, stream>>>(bout, temp, bias_f, temp_f, flag);
    transpose_cvt<<<dim3(3 * INNER_ / 32, D_ / 32), blk, 0, stream>>>(
        Wqkv, Wqkv_t, D_, 3 * INNER_, flag);
    transpose_cvt<<<dim3(D_ / 32, INNER_ / 32), blk, 0, stream>>>(
        Wout, Wout_t, INNER_, D_, flag);
    gemm_bt<0><<<dim3(M_ / 128, 3 * INNER_ / 128), blk, 0, stream>>>(
        xb, Wqkv_t, M_, 3 * INNER_, D_, q_ws, k_ws, v_nat, nullptr, nullptr,
        flag, temp_f);
    transpose_v<<<dim3(DH_ / 32, N_ / 32, B_ * H_), blk, 0, stream>>>(
        v_nat, vt_ws);
    attn_kernel<<<dim3(N_ / 128, B_ * H_), blk, 0, stream>>>(
        q_ws, k_ws, vt_ws, attn_out);
    gemm_bt<1><<<dim3(M_ / 128, D_ / 128), blk, 0, stream>>>(
        attn_out, Wout_t, M_, D_, INNER_, nullptr, nullptr, nullptr, d_out,
        bias_f, flag, temp_f);
}

// Round 2
// 319.810 us; speedup vs baseline: 1.5263x; 1.1136x over previous
//
#include <hip/hip_runtime.h>

// LSA_2147483648500: x[4,2048,1024](fp32) -> QKV proj -> 16-head attention
// (diag masked) -> out proj + bias. Internal bf16 MFMA; runtime dtype-detect.
//
// R10: attn_kernel restructured to 32x32x16 MFMA + T12 (cvt_pk_bf16 +
// permlane32_swap) P redistribution. S^T 32x32 output (col=qrow, row=key)
// feeds PV's B-operand with 8 permlane + 16 cvt_pk per 64-key tile,
// replacing 32 ds_bpermute + 8 pack2 (R9 counters: 8.4M LDS bank-conflict
// cycles, VALU 50%, Mfma 19% -> DS/VALU overhead bound). Row-sum and 1/l
// are now lane-local (one shfl_xor(32) total). Output LDS-staged to keep
// full-line stores. XCD-aware block remap: 16 q-blocks of one head share
// one XCD L2 (K/V 512KB x 8 heads = 4MB = one L2). GEMMs/transposes frozen.

using u16 = unsigned short;
typedef short short8 __attribute__((ext_vector_type(8)));
typedef float floatx4 __attribute__((ext_vector_type(4)));
typedef float floatx16 __attribute__((ext_vector_type(16)));
typedef unsigned int uint2v __attribute__((ext_vector_type(2)));

#define B_ 4
#define N_ 2048
#define H_ 16
#define DH_ 64
#define D_ 1024
#define INNER_ 1024
#define M_ (B_ * N_)   // 8192

__device__ __forceinline__ float bf2f(u16 h) {
    union { unsigned u; float f; } c; c.u = ((unsigned)h) << 16; return c.f;
}
__device__ __forceinline__ u16 f2bf(float f) {
    union { float f; unsigned u; } c; c.f = f;
    unsigned u = c.u + 0x7fffu + ((c.u >> 16) & 1u);
    return (u16)(u >> 16);
}
__device__ __forceinline__ unsigned cvtpk_bf16(float lo, float hi) {
    unsigned r;
    asm("v_cvt_pk_bf16_f32 %0, %1, %2" : "=v"(r) : "v"(lo), "v"(hi));
    return r;
}
__device__ __forceinline__ float fast_exp2(float x) {
#if defined(__has_builtin) && __has_builtin(__builtin_amdgcn_exp2f)
    return __builtin_amdgcn_exp2f(x);
#else
    return __expf(x * 0.69314718056f);
#endif
}
__device__ __forceinline__ void gl2lds16(const u16* g, u16* l) {
    __builtin_amdgcn_global_load_lds(
        (const __attribute__((address_space(1))) void*)g,
        (__attribute__((address_space(3))) void*)l, 16, 0, 0);
}

// -------- dtype detect: flag=1 if x's u16s look like bf16, else 0 ----------
__global__ void detect_dtype(const u16* __restrict__ x, int* __restrict__ flag) {
    __shared__ int cnt;
    if (threadIdx.x == 0) cnt = 0;
    __syncthreads();
    int c = 0;
    for (int i = threadIdx.x; i < 4096; i += 256) {
        int e = (x[i] >> 7) & 0xFF;
        if (e >= 107 && e <= 147) c++;
    }
    atomicAdd(&cnt, c);
    __syncthreads();
    if (threadIdx.x == 0) flag[0] = (cnt >= 3584) ? 1 : 0;
}

// -------- convert x (fp32 or bf16) -> bf16 ---------------------------------
__global__ __launch_bounds__(256) void convert_x(
    const void* __restrict__ in, u16* __restrict__ out, int n,
    const int* __restrict__ flag) {
    int f = flag[0];
    int i0 = (blockIdx.x * 256 + threadIdx.x) * 8;
    if (f) {
        const u16* p = (const u16*)in;
        for (int i = 0; i < 8; i++) out[i0 + i] = p[i0 + i];
    } else {
        const float* p = (const float*)in;
        for (int i = 0; i < 8; i++) out[i0 + i] = f2bf(p[i0 + i]);
    }
}

// -------- prep: bias -> fp32[1024], temperature -> fp32[1] -----------------
__global__ void prep_misc(const void* __restrict__ bias_in,
                          const void* __restrict__ temp_in,
                          float* __restrict__ bias_f, float* __restrict__ temp_f,
                          const int* __restrict__ flag) {
    int f = flag[0];
    for (int i = threadIdx.x; i < 1024; i += 256)
        bias_f[i] = f ? bf2f(((const u16*)bias_in)[i]) : ((const float*)bias_in)[i];
    if (threadIdx.x == 0)
        temp_f[0] = f ? bf2f(((const u16*)temp_in)[0]) : ((const float*)temp_in)[0];
}

// -------- transpose+convert: out[c][r] = bf16(in[r][c]) --------------------
__global__ __launch_bounds__(256) void transpose_cvt(
    const void* __restrict__ in, u16* __restrict__ out, int R, int C,
    const int* __restrict__ flag) {
    __shared__ u16 t[32][33];
    int f = flag[0];
    int tx = threadIdx.x & 31, ty = threadIdx.x >> 5;
    int c0 = blockIdx.x * 32, r0 = blockIdx.y * 32;
    for (int i = 0; i < 4; i++) {
        long idx = (long)(r0 + ty + i * 8) * C + c0 + tx;
        t[ty + i * 8][tx] = f ? ((const u16*)in)[idx] : f2bf(((const float*)in)[idx]);
    }
    __syncthreads();
    for (int i = 0; i < 4; i++)
        out[(long)(c0 + ty + i * 8) * R + r0 + tx] = t[tx][ty + i * 8];
}

// -------- transpose v: per-bh [N][64] -> [64][N], bf16 ----------------------
__global__ __launch_bounds__(256) void transpose_v(
    const u16* __restrict__ in, u16* __restrict__ out) {
    __shared__ u16 t[32][33];
    const int bh = blockIdx.z;
    const u16* src = in + (long)bh * N_ * DH_;
    u16* dst = out + (long)bh * DH_ * N_;
    int tx = threadIdx.x & 31, ty = threadIdx.x >> 5;
    int r0 = blockIdx.y * 32;   // n rows
    int c0 = blockIdx.x * 32;   // dh cols
    for (int i = 0; i < 4; i++)
        t[ty + i * 8][tx] = src[(long)(r0 + ty + i * 8) * DH_ + c0 + tx];
    __syncthreads();
    for (int i = 0; i < 4; i++)
        dst[(long)(c0 + ty + i * 8) * N_ + r0 + tx] = t[tx][ty + i * 8];
}

// ---------------- GEMM: C[M,N] = A[M,K] * Bt[N,K]^T, bf16 MFMA --------------
// 128x128 tile, BK=32, 4 waves 2x2, swizzled LDS via source-permuted
// global_load_lds. MODE 0: LDS-staged coalesced scatter to q (pre-scaled),
// k, v — all [BH][N][DH]. MODE 1: +bias, LDS-staged coalesced store
// (full-line float4 / short8 per lane) to outv.
template <int MODE>
__global__ __launch_bounds__(256) void gemm_bt(
    const u16* __restrict__ A, const u16* __restrict__ Bt,
    int M, int N, int K,
    u16* __restrict__ out0, u16* __restrict__ out1, u16* __restrict__ out2,
    void* __restrict__ outv, const float* __restrict__ bias,
    const int* __restrict__ flag, const float* __restrict__ temp_f) {
    __shared__ __align__(16) u16 lA[128 * 32];
    __shared__ __align__(16) u16 lB[128 * 32];
    const int tid = threadIdx.x;
    const int lane = tid & 63;
    const int w = tid >> 6;
    const int wr = w >> 1, wc = w & 1;
    const int qd = lane >> 4, qm = lane & 15;
    const long m0 = (long)blockIdx.x * 128;
    const long n0 = (long)blockIdx.y * 128;

    floatx4 acc[4][4];
    for (int i = 0; i < 4; i++)
        for (int j = 0; j < 4; j++) acc[i][j] = (floatx4){0.f, 0.f, 0.f, 0.f};

    const int arow = lane >> 2;
    const int acol = ((lane & 3) ^ ((lane >> 3) & 3)) * 8;
    const int swz = (qm >> 1) & 3;

    for (int k0 = 0; k0 < K; k0 += 32) {
        for (int i = 0; i < 2; i++) {
            int c = w + i * 4;
            gl2lds16(A + (m0 + c * 16 + arow) * K + k0 + acol, lA + c * 512);
            gl2lds16(Bt + (n0 + c * 16 + arow) * K + k0 + acol, lB + c * 512);
        }
        __syncthreads();
        short8 af[4], bfr[4];
        for (int mt = 0; mt < 4; mt++)
            af[mt] = *(const short8*)&lA[(wr * 64 + mt * 16 + qm) * 32 + (qd ^ swz) * 8];
        for (int nt = 0; nt < 4; nt++)
            bfr[nt] = *(const short8*)&lB[(wc * 64 + nt * 16 + qm) * 32 + (qd ^ swz) * 8];
        for (int mt = 0; mt < 4; mt++)
            for (int nt = 0; nt < 4; nt++)
                acc[mt][nt] = __builtin_amdgcn_mfma_f32_16x16x32_bf16(
                    af[mt], bfr[nt], acc[mt][nt], 0, 0, 0);
        __syncthreads();
    }

    if (MODE == 0) {
        // LDS-staged epilogue: two 64-row halves; each 128B output line is
        // written once, fully, by a single dwordx4-per-lane instruction.
        const float qscale = __expf(temp_f[0]) * 1.44269504089f;
        __shared__ __align__(16) u16 lC[64 * 132];
        for (int half = 0; half < 2; half++) {
            __syncthreads();
            if (wr == half) {
                for (int nt = 0; nt < 4; nt++) {
                    long ng = n0 + wc * 64 + nt * 16 + qm;
                    float sc = ((ng >> 10) == 0) ? qscale : 1.0f;
                    for (int mt = 0; mt < 4; mt++)
                        for (int r = 0; r < 4; r++)
                            lC[(mt * 16 + qd * 4 + r) * 132 + wc * 64 + nt * 16 + qm] =
                                f2bf(acc[mt][nt][r] * sc);
                }
            }
            __syncthreads();
            for (int i = 0; i < 4; i++) {
                int row = (tid >> 4) + i * 16;       // 0..63
                int c = (tid & 15) * 8;              // col, 8-aligned
                long m = m0 + half * 64 + row;
                long ngc = n0 + c;
                int part = (int)(ngc >> 10);
                int rem = (int)(ngc & 1023);
                int hh = rem >> 6, dh = rem & 63;
                long bb = m >> 11, n = m & 2047;
                long idx = ((bb * H_ + hh) * N_ + n) * DH_ + dh;
                short8 vv = *(const short8*)&lC[row * 132 + c];
                u16* dst = (part == 0) ? out0 : (part == 1) ? out1 : out2;
                *(short8*)&dst[idx] = vv;
            }
        }
    } else {
        // LDS-staged fp32 epilogue: stage acc+bias into lCf (padded stride
        // 132 dwords), then cooperative full-line stores.
        const int f = flag[0];
        __shared__ __align__(16) float lCf[64 * 132];
        for (int half = 0; half < 2; half++) {
            __syncthreads();
            if (wr == half) {
                for (int nt = 0; nt < 4; nt++) {
                    long ng = n0 + wc * 64 + nt * 16 + qm;
                    float bv = bias[ng];
                    for (int mt = 0; mt < 4; mt++)
                        for (int r = 0; r < 4; r++)
                            lCf[(mt * 16 + qd * 4 + r) * 132 + wc * 64 + nt * 16 + qm] =
                                acc[mt][nt][r] + bv;
                }
            }
            __syncthreads();
            if (f) {
                for (int i = 0; i < 4; i++) {
                    int row = (tid >> 4) + i * 16;   // 0..63
                    int c = (tid & 15) * 8;          // col, 8-aligned
                    long m = m0 + half * 64 + row;
                    u16 tmp[8];
                    for (int j = 0; j < 8; j++) tmp[j] = f2bf(lCf[row * 132 + c + j]);
                    *(short8*)&((u16*)outv)[m * N + n0 + c] = *(const short8*)tmp;
                }
            } else {
                for (int i = 0; i < 8; i++) {
                    int row = (tid >> 5) + i * 8;    // 0..63
                    int c = (tid & 31) * 4;          // col, 4-aligned fp32
                    long m = m0 + half * 64 + row;
                    floatx4 vv = *(const floatx4*)&lCf[row * 132 + c];
                    *(floatx4*)&((float*)outv)[m * N + n0 + c] = vv;
                }
            }
        }
    }
}

// ---------------- flash attention, 32x32 MFMA + permlane P-redistribute ----
// grid = (16, 64) remapped XCD-aware. 256 thr = 4 waves; wave w owns qrows
// qbase..qbase+31 (col dim). S^T = K*Q^T via mfma_32x32x16: lane(ln,h)
// holds S^T[key=(r&3)+8*(r>>2)+4h+32kt][qrow=ln]. P->bf16 via cvt_pk;
// one permlane32_swap per dword pair builds PV's B-frag (keys h*8+j).
// O^T accumulated (col=qrow); 1/l is lane-local. Output LDS-staged.
__global__ __launch_bounds__(256) void attn_kernel(
    const u16* __restrict__ q_ws, const u16* __restrict__ k_ws,
    const u16* __restrict__ vt_ws, u16* __restrict__ out) {
    __shared__ __align__(16) u16 lbuf[2 * 64 * 64];   // lK | lV (16 KiB)
    u16* lK = lbuf;
    u16* lV = lbuf + 64 * 64;
    const int tid = threadIdx.x, lane = tid & 63, w = tid >> 6;
    const int ln = lane & 31, h = lane >> 5;

    // XCD-aware remap: 8 consecutive-linear classes (xcd) x 8 heads x 16 q0
    int linear = blockIdx.y * 16 + blockIdx.x;
    int bh = (linear & 7) * 8 + (linear >> 7);
    int q0 = ((linear >> 3) & 15) * 128;
    const int b = bh >> 4, hd = bh & 15;

    const u16* Q = q_ws + (long)bh * N_ * DH_;
    const u16* Kp = k_ws + (long)bh * N_ * DH_;
    const u16* Vt = vt_ws + (long)bh * DH_ * N_;

    const int qbase = q0 + w * 32;
    const int qrow = qbase + ln;          // this lane's q row (both halves)

    // Q B-frags (pre-scaled by exp(temp)*log2e in gemm MODE 0):
    // qa[c] = Q[qrow][c*16 + h*8 .. +8]
    short8 qa[4];
#pragma unroll
    for (int c = 0; c < 4; c++)
        qa[c] = *(const short8*)&Q[(long)qrow * DH_ + c * 16 + h * 8];

    floatx16 accO[2];
#pragma unroll
    for (int i = 0; i < 16; i++) { accO[0][i] = 0.f; accO[1][i] = 0.f; }
    float lacc = 0.f;

    const int srow = lane >> 3;
    const int scol = ((lane & 7) ^ srow) * 8;
    const int rsw = (ln & 7);             // read-side granule XOR

    for (int k0 = 0; k0 < N_; k0 += 64) {
        for (int i = 0; i < 2; i++) {
            int c = w + i * 4;
            gl2lds16(Kp + (long)(k0 + c * 8 + srow) * DH_ + scol, lK + c * 512);
            gl2lds16(Vt + (long)(c * 8 + srow) * N_ + k0 + scol, lV + c * 512);
        }
        __syncthreads();
        const bool diag = ((unsigned)(qbase - k0) < 64u);

#pragma unroll
        for (int kt = 0; kt < 2; kt++) {
            // S^T tile: [32 keys][32 qrows], contraction over DH=64
            floatx16 accS;
#pragma unroll
            for (int i = 0; i < 16; i++) accS[i] = 0.f;
#pragma unroll
            for (int c = 0; c < 4; c++) {
                short8 kf = *(const short8*)
                    &lK[(kt * 32 + ln) * 64 + ((c * 2 + h) ^ rsw) * 8];
                accS = __builtin_amdgcn_mfma_f32_32x32x16_bf16(
                    kf, qa[c], accS, 0, 0, 0);
            }
            // p = exp2(S^T); diag zero; lane-local row-sum (qrow fixed).
            float rs = 0.f;
#pragma unroll
            for (int r = 0; r < 16; r++) {
                float pv = fast_exp2(accS[r]);
                if (diag) {
                    int key = k0 + kt * 32 + (r & 3) + 8 * (r >> 2) + 4 * h;
                    if (key == qrow) pv = 0.f;
                }
                accS[r] = pv;
                rs += pv;
            }
            lacc += rs;
            // PV: per 16-key chunk build B-frag (keys h*8+j) via
            // cvt_pk pairs + permlane32_swap, then 2 dt MFMAs.
#pragma unroll
            for (int ch = 0; ch < 2; ch++) {
                const int rb = ch * 8;
                unsigned d01 = cvtpk_bf16(accS[rb + 0], accS[rb + 1]);
                unsigned d23 = cvtpk_bf16(accS[rb + 2], accS[rb + 3]);
                unsigned d45 = cvtpk_bf16(accS[rb + 4], accS[rb + 5]);
                unsigned d67 = cvtpk_bf16(accS[rb + 6], accS[rb + 7]);
                uint2v s1 = __builtin_amdgcn_permlane32_swap(d01, d45, false, false);
                uint2v s2 = __builtin_amdgcn_permlane32_swap(d23, d67, false, false);
                union { unsigned u[4]; short8 v; } pf;
                pf.u[0] = s1[0]; pf.u[1] = s2[0]; pf.u[2] = s1[1]; pf.u[3] = s2[1];
                const int cc = kt * 2 + ch;
#pragma unroll
                for (int dt = 0; dt < 2; dt++) {
                    short8 vf = *(const short8*)
                        &lV[(dt * 32 + ln) * 64 + ((cc * 2 + h) ^ rsw) * 8];
                    accO[dt] = __builtin_amdgcn_mfma_f32_32x32x16_bf16(
                        vf, pf.v, accO[dt], 0, 0, 0);
                }
            }
        }
        __syncthreads();
    }

    // normalizer: lane and lane+32 share qrow, disjoint keys.
    lacc += __shfl_xor(lacc, 32, 64);
    const float inv = 1.f / lacc;

    // Stage O[q 32][d 64] bf16 per wave (4 KiB each) into lbuf, swizzled
    // 16B granules (G ^= row&7), then cooperative full-line stores.
    u16* stg = (u16*)((char*)lbuf + w * 4096);
#pragma unroll
    for (int dt = 0; dt < 2; dt++)
#pragma unroll
        for (int q2 = 0; q2 < 4; q2++) {
            // regs q2*4..+3 -> d = dt*32 + 8*q2 + 4h + 0..3
            union { unsigned u[2]; unsigned long long ull; } ee;
            ee.u[0] = cvtpk_bf16(accO[dt][q2 * 4 + 0] * inv,
                                 accO[dt][q2 * 4 + 1] * inv);
            ee.u[1] = cvtpk_bf16(accO[dt][q2 * 4 + 2] * inv,
                                 accO[dt][q2 * 4 + 3] * inv);
            int G = dt * 4 + q2;
            *(unsigned long long*)
                &stg[ln * 64 + ((G ^ rsw) * 8) + h * 4] = ee.ull;
        }
    __syncthreads();
#pragma unroll
    for (int p = 0; p < 4; p++) {
        int R = p * 32 + (tid >> 3);          // 0..127 (wave R>>5's rows)
        int G = tid & 7;
        const u16* src = (const u16*)((char*)lbuf + (R >> 5) * 4096
                          + (R & 31) * 128 + ((G ^ (R & 7)) * 16));
        short8 vv = *(const short8*)src;
        *(short8*)&out[((long)(b * N_ + q0 + R)) * INNER_ + hd * DH_ + G * 8] = vv;
    }
}

extern "C" void kernel_launch(void* const* d_in, const int* in_sizes, int n_in,
                              void* d_out, int out_size, void* d_ws, size_t ws_size,
                              hipStream_t stream) {
    const void* x    = d_in[0];
    const void* Wqkv = d_in[1];
    const void* Wout = d_in[2];
    const void* bout = d_in[3];
    const void* temp = d_in[4];

    char* base = (char*)d_ws;
    int*   flag    = (int*)base;
    float* temp_f  = (float*)(base + 16);
    float* bias_f  = (float*)(base + 32);
    u16* xb      = (u16*)(base + 8192);
    u16* Wqkv_t  = xb + (long)M_ * D_;
    u16* Wout_t  = Wqkv_t + 3072 * 1024;
    u16* q_ws    = Wout_t + 1024 * 1024;
    u16* k_ws    = q_ws + (long)B_ * H_ * N_ * DH_;
    u16* vt_ws   = k_ws + (long)B_ * H_ * N_ * DH_;
    u16* attn_out = vt_ws + (long)B_ * H_ * N_ * DH_;
    u16* v_nat   = attn_out;  // alias: dead until attn_kernel writes it

    dim3 blk(256);
    detect_dtype<<<1, blk, 0, stream>>>((const u16*)x, flag);
    convert_x<<<dim3(M_ * D_ / (256 * 8)), blk, 0, stream>>>(x, xb, M_ * D_, flag);
    prep_misc<<<1, blk, 0, stream>>>(bout, temp, bias_f, temp_f, flag);
    transpose_cvt<<<dim3(3 * INNER_ / 32, D_ / 32), blk, 0, stream>>>(
        Wqkv, Wqkv_t, D_, 3 * INNER_, flag);
    transpose_cvt<<<dim3(D_ / 32, INNER_ / 32), blk, 0, stream>>>(
        Wout, Wout_t, INNER_, D_, flag);
    gemm_bt<0><<<dim3(M_ / 128, 3 * INNER_ / 128), blk, 0, stream>>>(
        xb, Wqkv_t, M_, 3 * INNER_, D_, q_ws, k_ws, v_nat, nullptr, nullptr,
        flag, temp_f);
    transpose_v<<<dim3(DH_ / 32, N_ / 32, B_ * H_), blk, 0, stream>>>(
        v_nat, vt_ws);
    attn_kernel<<<dim3(N_ / 128, B_ * H_), blk, 0, stream>>>(
        q_ws, k_ws, vt_ws, attn_out);
    gemm_bt<1><<<dim3(M_ / 128, D_ / 128), blk, 0, stream>>>(
        attn_out, Wout_t, M_, D_, INNER_, nullptr, nullptr, nullptr, d_out,
        bias_f, flag, temp_f);
}

// Round 3
// 302.724 us; speedup vs baseline: 1.6125x; 1.0564x over previous
//
#include <hip/hip_runtime.h>

// LSA_2147483648500: x[4,2048,1024](fp32) -> QKV proj -> 16-head attention
// (diag masked) -> out proj + bias. Internal bf16 MFMA; runtime dtype-detect.
//
// R11: attn_kernel gets (1) 64 q-rows/wave (2 accumulator groups) so each
// K/V LDS fragment read feeds two MFMAs — halves per-FLOP LDS read traffic
// (R10 counters: conflicts flat at 8.5M = b128 reads themselves; LDS-BW
// term ~40us) — and (2) K/V double-buffer prefetch: stage tile t+1 BEFORE
// computing tile t, one barrier per tile, so L2 latency hides under
// compute (R10 issued loads right before the draining barrier = serial
// stall every tile). 512 blocks = exactly 2/CU; LDS 32KB/block.
// GEMMs/transposes frozen from R10.

using u16 = unsigned short;
typedef short short8 __attribute__((ext_vector_type(8)));
typedef float floatx4 __attribute__((ext_vector_type(4)));
typedef float floatx16 __attribute__((ext_vector_type(16)));
typedef unsigned int uint2v __attribute__((ext_vector_type(2)));

#define B_ 4
#define N_ 2048
#define H_ 16
#define DH_ 64
#define D_ 1024
#define INNER_ 1024
#define M_ (B_ * N_)   // 8192

__device__ __forceinline__ float bf2f(u16 h) {
    union { unsigned u; float f; } c; c.u = ((unsigned)h) << 16; return c.f;
}
__device__ __forceinline__ u16 f2bf(float f) {
    union { float f; unsigned u; } c; c.f = f;
    unsigned u = c.u + 0x7fffu + ((c.u >> 16) & 1u);
    return (u16)(u >> 16);
}
__device__ __forceinline__ unsigned cvtpk_bf16(float lo, float hi) {
    unsigned r;
    asm("v_cvt_pk_bf16_f32 %0, %1, %2" : "=v"(r) : "v"(lo), "v"(hi));
    return r;
}
__device__ __forceinline__ float fast_exp2(float x) {
#if defined(__has_builtin) && __has_builtin(__builtin_amdgcn_exp2f)
    return __builtin_amdgcn_exp2f(x);
#else
    return __expf(x * 0.69314718056f);
#endif
}
__device__ __forceinline__ void gl2lds16(const u16* g, u16* l) {
    __builtin_amdgcn_global_load_lds(
        (const __attribute__((address_space(1))) void*)g,
        (__attribute__((address_space(3))) void*)l, 16, 0, 0);
}

// -------- dtype detect: flag=1 if x's u16s look like bf16, else 0 ----------
__global__ void detect_dtype(const u16* __restrict__ x, int* __restrict__ flag) {
    __shared__ int cnt;
    if (threadIdx.x == 0) cnt = 0;
    __syncthreads();
    int c = 0;
    for (int i = threadIdx.x; i < 4096; i += 256) {
        int e = (x[i] >> 7) & 0xFF;
        if (e >= 107 && e <= 147) c++;
    }
    atomicAdd(&cnt, c);
    __syncthreads();
    if (threadIdx.x == 0) flag[0] = (cnt >= 3584) ? 1 : 0;
}

// -------- convert x (fp32 or bf16) -> bf16 ---------------------------------
__global__ __launch_bounds__(256) void convert_x(
    const void* __restrict__ in, u16* __restrict__ out, int n,
    const int* __restrict__ flag) {
    int f = flag[0];
    int i0 = (blockIdx.x * 256 + threadIdx.x) * 8;
    if (f) {
        const u16* p = (const u16*)in;
        for (int i = 0; i < 8; i++) out[i0 + i] = p[i0 + i];
    } else {
        const float* p = (const float*)in;
        for (int i = 0; i < 8; i++) out[i0 + i] = f2bf(p[i0 + i]);
    }
}

// -------- prep: bias -> fp32[1024], temperature -> fp32[1] -----------------
__global__ void prep_misc(const void* __restrict__ bias_in,
                          const void* __restrict__ temp_in,
                          float* __restrict__ bias_f, float* __restrict__ temp_f,
                          const int* __restrict__ flag) {
    int f = flag[0];
    for (int i = threadIdx.x; i < 1024; i += 256)
        bias_f[i] = f ? bf2f(((const u16*)bias_in)[i]) : ((const float*)bias_in)[i];
    if (threadIdx.x == 0)
        temp_f[0] = f ? bf2f(((const u16*)temp_in)[0]) : ((const float*)temp_in)[0];
}

// -------- transpose+convert: out[c][r] = bf16(in[r][c]) --------------------
__global__ __launch_bounds__(256) void transpose_cvt(
    const void* __restrict__ in, u16* __restrict__ out, int R, int C,
    const int* __restrict__ flag) {
    __shared__ u16 t[32][33];
    int f = flag[0];
    int tx = threadIdx.x & 31, ty = threadIdx.x >> 5;
    int c0 = blockIdx.x * 32, r0 = blockIdx.y * 32;
    for (int i = 0; i < 4; i++) {
        long idx = (long)(r0 + ty + i * 8) * C + c0 + tx;
        t[ty + i * 8][tx] = f ? ((const u16*)in)[idx] : f2bf(((const float*)in)[idx]);
    }
    __syncthreads();
    for (int i = 0; i < 4; i++)
        out[(long)(c0 + ty + i * 8) * R + r0 + tx] = t[tx][ty + i * 8];
}

// -------- transpose v: per-bh [N][64] -> [64][N], bf16 ----------------------
__global__ __launch_bounds__(256) void transpose_v(
    const u16* __restrict__ in, u16* __restrict__ out) {
    __shared__ u16 t[32][33];
    const int bh = blockIdx.z;
    const u16* src = in + (long)bh * N_ * DH_;
    u16* dst = out + (long)bh * DH_ * N_;
    int tx = threadIdx.x & 31, ty = threadIdx.x >> 5;
    int r0 = blockIdx.y * 32;   // n rows
    int c0 = blockIdx.x * 32;   // dh cols
    for (int i = 0; i < 4; i++)
        t[ty + i * 8][tx] = src[(long)(r0 + ty + i * 8) * DH_ + c0 + tx];
    __syncthreads();
    for (int i = 0; i < 4; i++)
        dst[(long)(c0 + ty + i * 8) * N_ + r0 + tx] = t[tx][ty + i * 8];
}

// ---------------- GEMM: C[M,N] = A[M,K] * Bt[N,K]^T, bf16 MFMA --------------
// 128x128 tile, BK=32, 4 waves 2x2, swizzled LDS via source-permuted
// global_load_lds. MODE 0: LDS-staged coalesced scatter to q (pre-scaled),
// k, v — all [BH][N][DH]. MODE 1: +bias, LDS-staged coalesced store
// (full-line float4 / short8 per lane) to outv.
template <int MODE>
__global__ __launch_bounds__(256) void gemm_bt(
    const u16* __restrict__ A, const u16* __restrict__ Bt,
    int M, int N, int K,
    u16* __restrict__ out0, u16* __restrict__ out1, u16* __restrict__ out2,
    void* __restrict__ outv, const float* __restrict__ bias,
    const int* __restrict__ flag, const float* __restrict__ temp_f) {
    __shared__ __align__(16) u16 lA[128 * 32];
    __shared__ __align__(16) u16 lB[128 * 32];
    const int tid = threadIdx.x;
    const int lane = tid & 63;
    const int w = tid >> 6;
    const int wr = w >> 1, wc = w & 1;
    const int qd = lane >> 4, qm = lane & 15;
    const long m0 = (long)blockIdx.x * 128;
    const long n0 = (long)blockIdx.y * 128;

    floatx4 acc[4][4];
    for (int i = 0; i < 4; i++)
        for (int j = 0; j < 4; j++) acc[i][j] = (floatx4){0.f, 0.f, 0.f, 0.f};

    const int arow = lane >> 2;
    const int acol = ((lane & 3) ^ ((lane >> 3) & 3)) * 8;
    const int swz = (qm >> 1) & 3;

    for (int k0 = 0; k0 < K; k0 += 32) {
        for (int i = 0; i < 2; i++) {
            int c = w + i * 4;
            gl2lds16(A + (m0 + c * 16 + arow) * K + k0 + acol, lA + c * 512);
            gl2lds16(Bt + (n0 + c * 16 + arow) * K + k0 + acol, lB + c * 512);
        }
        __syncthreads();
        short8 af[4], bfr[4];
        for (int mt = 0; mt < 4; mt++)
            af[mt] = *(const short8*)&lA[(wr * 64 + mt * 16 + qm) * 32 + (qd ^ swz) * 8];
        for (int nt = 0; nt < 4; nt++)
            bfr[nt] = *(const short8*)&lB[(wc * 64 + nt * 16 + qm) * 32 + (qd ^ swz) * 8];
        for (int mt = 0; mt < 4; mt++)
            for (int nt = 0; nt < 4; nt++)
                acc[mt][nt] = __builtin_amdgcn_mfma_f32_16x16x32_bf16(
                    af[mt], bfr[nt], acc[mt][nt], 0, 0, 0);
        __syncthreads();
    }

    if (MODE == 0) {
        // LDS-staged epilogue: two 64-row halves; each 128B output line is
        // written once, fully, by a single dwordx4-per-lane instruction.
        const float qscale = __expf(temp_f[0]) * 1.44269504089f;
        __shared__ __align__(16) u16 lC[64 * 132];
        for (int half = 0; half < 2; half++) {
            __syncthreads();
            if (wr == half) {
                for (int nt = 0; nt < 4; nt++) {
                    long ng = n0 + wc * 64 + nt * 16 + qm;
                    float sc = ((ng >> 10) == 0) ? qscale : 1.0f;
                    for (int mt = 0; mt < 4; mt++)
                        for (int r = 0; r < 4; r++)
                            lC[(mt * 16 + qd * 4 + r) * 132 + wc * 64 + nt * 16 + qm] =
                                f2bf(acc[mt][nt][r] * sc);
                }
            }
            __syncthreads();
            for (int i = 0; i < 4; i++) {
                int row = (tid >> 4) + i * 16;       // 0..63
                int c = (tid & 15) * 8;              // col, 8-aligned
                long m = m0 + half * 64 + row;
                long ngc = n0 + c;
                int part = (int)(ngc >> 10);
                int rem = (int)(ngc & 1023);
                int hh = rem >> 6, dh = rem & 63;
                long bb = m >> 11, n = m & 2047;
                long idx = ((bb * H_ + hh) * N_ + n) * DH_ + dh;
                short8 vv = *(const short8*)&lC[row * 132 + c];
                u16* dst = (part == 0) ? out0 : (part == 1) ? out1 : out2;
                *(short8*)&dst[idx] = vv;
            }
        }
    } else {
        // LDS-staged fp32 epilogue: stage acc+bias into lCf (padded stride
        // 132 dwords), then cooperative full-line stores.
        const int f = flag[0];
        __shared__ __align__(16) float lCf[64 * 132];
        for (int half = 0; half < 2; half++) {
            __syncthreads();
            if (wr == half) {
                for (int nt = 0; nt < 4; nt++) {
                    long ng = n0 + wc * 64 + nt * 16 + qm;
                    float bv = bias[ng];
                    for (int mt = 0; mt < 4; mt++)
                        for (int r = 0; r < 4; r++)
                            lCf[(mt * 16 + qd * 4 + r) * 132 + wc * 64 + nt * 16 + qm] =
                                acc[mt][nt][r] + bv;
                }
            }
            __syncthreads();
            if (f) {
                for (int i = 0; i < 4; i++) {
                    int row = (tid >> 4) + i * 16;   // 0..63
                    int c = (tid & 15) * 8;          // col, 8-aligned
                    long m = m0 + half * 64 + row;
                    u16 tmp[8];
                    for (int j = 0; j < 8; j++) tmp[j] = f2bf(lCf[row * 132 + c + j]);
                    *(short8*)&((u16*)outv)[m * N + n0 + c] = *(const short8*)tmp;
                }
            } else {
                for (int i = 0; i < 8; i++) {
                    int row = (tid >> 5) + i * 8;    // 0..63
                    int c = (tid & 31) * 4;          // col, 4-aligned fp32
                    long m = m0 + half * 64 + row;
                    floatx4 vv = *(const floatx4*)&lCf[row * 132 + c];
                    *(floatx4*)&((float*)outv)[m * N + n0 + c] = vv;
                }
            }
        }
    }
}

// ---------------- flash attention, 32x32 MFMA, 64 q-rows/wave, dbuf --------
// grid = (8, 64) remapped XCD-aware. 256 thr = 4 waves; wave w owns qrows
// qbase..qbase+63 as 2 groups of 32 (each K/V LDS fragment feeds both
// groups' MFMAs). K/V double-buffered: tile t+1 staged before computing
// tile t; one barrier per tile. S^T = K*Q^T via mfma_32x32x16: lane(ln,h)
// holds S^T[key=(r&3)+8*(r>>2)+4h+32kt][qrow=ln]. P->bf16 via cvt_pk;
// permlane32_swap builds PV's B-frag. 1/l lane-local. Output LDS-staged.
__global__ __launch_bounds__(256) void attn_kernel(
    const u16* __restrict__ q_ws, const u16* __restrict__ k_ws,
    const u16* __restrict__ vt_ws, u16* __restrict__ out) {
    __shared__ __align__(16) u16 lbuf[2 * 2 * 64 * 64];  // 32 KiB: 2 bufs x (K|V)
    const int tid = threadIdx.x, lane = tid & 63, w = tid >> 6;
    const int ln = lane & 31, h = lane >> 5;

    // XCD-aware remap: xcd = linear&7; 8 q-blocks of one head share an XCD.
    int linear = blockIdx.y * 8 + blockIdx.x;
    int bh = (linear & 7) * 8 + ((linear >> 6) & 7);
    int q0 = ((linear >> 3) & 7) * 256;
    const int b = bh >> 4, hd = bh & 15;

    const u16* Q = q_ws + (long)bh * N_ * DH_;
    const u16* Kp = k_ws + (long)bh * N_ * DH_;
    const u16* Vt = vt_ws + (long)bh * DH_ * N_;

    const int qbase = q0 + w * 64;

    // Q B-frags (pre-scaled by exp(temp)*log2e in gemm MODE 0)
    short8 qa[2][4];
#pragma unroll
    for (int g = 0; g < 2; g++)
#pragma unroll
        for (int c = 0; c < 4; c++)
            qa[g][c] = *(const short8*)
                &Q[(long)(qbase + g * 32 + ln) * DH_ + c * 16 + h * 8];

    floatx16 accO[2][2];
#pragma unroll
    for (int i = 0; i < 16; i++) {
        accO[0][0][i] = 0.f; accO[0][1][i] = 0.f;
        accO[1][0][i] = 0.f; accO[1][1][i] = 0.f;
    }
    float lacc[2] = {0.f, 0.f};

    const int srow = lane >> 3;
    const int scol = ((lane & 7) ^ srow) * 8;
    const int rsw = (ln & 7);             // read-side granule XOR

    // prologue: stage tile 0 into buffer 0
    {
        u16* nK = lbuf;
        u16* nV = lbuf + 4096;
        for (int i = 0; i < 2; i++) {
            int c = w + i * 4;
            gl2lds16(Kp + (long)(c * 8 + srow) * DH_ + scol, nK + c * 512);
            gl2lds16(Vt + (long)(c * 8 + srow) * N_ + scol, nV + c * 512);
        }
    }
    __syncthreads();

    for (int t = 0; t < 32; t++) {
        const int k0 = t * 64;
        const u16* lK = lbuf + (t & 1) * 8192;
        const u16* lV = lK + 4096;
        // prefetch next tile into the other buffer (drained by the barrier
        // at the END of this iteration -> latency hides under compute)
        if (t < 31) {
            u16* nK = lbuf + ((t + 1) & 1) * 8192;
            u16* nV = nK + 4096;
            for (int i = 0; i < 2; i++) {
                int c = w + i * 4;
                gl2lds16(Kp + (long)(k0 + 64 + c * 8 + srow) * DH_ + scol,
                         nK + c * 512);
                gl2lds16(Vt + (long)(c * 8 + srow) * N_ + k0 + 64 + scol,
                         nV + c * 512);
            }
        }

#pragma unroll
        for (int kt = 0; kt < 2; kt++) {
            floatx16 accS[2];
#pragma unroll
            for (int i = 0; i < 16; i++) { accS[0][i] = 0.f; accS[1][i] = 0.f; }
#pragma unroll
            for (int c = 0; c < 4; c++) {
                short8 kf = *(const short8*)
                    &lK[(kt * 32 + ln) * 64 + ((c * 2 + h) ^ rsw) * 8];
                accS[0] = __builtin_amdgcn_mfma_f32_32x32x16_bf16(
                    kf, qa[0][c], accS[0], 0, 0, 0);
                accS[1] = __builtin_amdgcn_mfma_f32_32x32x16_bf16(
                    kf, qa[1][c], accS[1], 0, 0, 0);
            }
            // softmax numerator (diag-masked) + lane-local row sums
#pragma unroll
            for (int g = 0; g < 2; g++) {
#pragma unroll
                for (int r = 0; r < 16; r++)
                    accS[g][r] = fast_exp2(accS[g][r]);
                if ((qbase + g * 32) == (k0 + kt * 32)) {
#pragma unroll
                    for (int r = 0; r < 16; r++) {
                        int kk = (r & 3) + 8 * (r >> 2) + 4 * h;
                        if (kk == ln) accS[g][r] = 0.f;
                    }
                }
                float rs = (((accS[g][0] + accS[g][1]) + (accS[g][2] + accS[g][3]))
                          + ((accS[g][4] + accS[g][5]) + (accS[g][6] + accS[g][7])))
                         + (((accS[g][8] + accS[g][9]) + (accS[g][10] + accS[g][11]))
                          + ((accS[g][12] + accS[g][13]) + (accS[g][14] + accS[g][15])));
                lacc[g] += rs;
            }
            // PV: per 16-key chunk build both groups' B-frags, read V once
#pragma unroll
            for (int ch = 0; ch < 2; ch++) {
                const int rb = ch * 8;
                short8 pfv[2];
#pragma unroll
                for (int g = 0; g < 2; g++) {
                    unsigned d01 = cvtpk_bf16(accS[g][rb + 0], accS[g][rb + 1]);
                    unsigned d23 = cvtpk_bf16(accS[g][rb + 2], accS[g][rb + 3]);
                    unsigned d45 = cvtpk_bf16(accS[g][rb + 4], accS[g][rb + 5]);
                    unsigned d67 = cvtpk_bf16(accS[g][rb + 6], accS[g][rb + 7]);
                    uint2v s1 = __builtin_amdgcn_permlane32_swap(d01, d45, false, false);
                    uint2v s2 = __builtin_amdgcn_permlane32_swap(d23, d67, false, false);
                    union { unsigned u[4]; short8 v; } pf;
                    pf.u[0] = s1[0]; pf.u[1] = s2[0]; pf.u[2] = s1[1]; pf.u[3] = s2[1];
                    pfv[g] = pf.v;
                }
                const int cc = kt * 2 + ch;
#pragma unroll
                for (int dt = 0; dt < 2; dt++) {
                    short8 vf = *(const short8*)
                        &lV[(dt * 32 + ln) * 64 + ((cc * 2 + h) ^ rsw) * 8];
                    accO[0][dt] = __builtin_amdgcn_mfma_f32_32x32x16_bf16(
                        vf, pfv[0], accO[0][dt], 0, 0, 0);
                    accO[1][dt] = __builtin_amdgcn_mfma_f32_32x32x16_bf16(
                        vf, pfv[1], accO[1][dt], 0, 0, 0);
                }
            }
        }
        __syncthreads();
    }

    // normalize + stage O (bf16, swizzled 16B granules) into lbuf, then
    // cooperative full-line stores. lane & lane+32 share qrow, disjoint keys.
#pragma unroll
    for (int g = 0; g < 2; g++) {
        float s = lacc[g];
        s += __shfl_xor(s, 32, 64);
        const float inv = 1.f / s;
        u16* stg = (u16*)((char*)lbuf + w * 8192 + g * 4096);
#pragma unroll
        for (int dt = 0; dt < 2; dt++)
#pragma unroll
            for (int q2 = 0; q2 < 4; q2++) {
                union { unsigned u[2]; unsigned long long ull; } ee;
                ee.u[0] = cvtpk_bf16(accO[g][dt][q2 * 4 + 0] * inv,
                                     accO[g][dt][q2 * 4 + 1] * inv);
                ee.u[1] = cvtpk_bf16(accO[g][dt][q2 * 4 + 2] * inv,
                                     accO[g][dt][q2 * 4 + 3] * inv);
                int G = dt * 4 + q2;
                *(unsigned long long*)
                    &stg[ln * 64 + ((G ^ rsw) * 8) + h * 4] = ee.ull;
            }
    }
    __syncthreads();
#pragma unroll
    for (int p = 0; p < 8; p++) {
        int R = p * 32 + (tid >> 3);          // 0..255
        int G = tid & 7;
        const u16* src = (const u16*)((char*)lbuf + (R >> 6) * 8192
                          + ((R >> 5) & 1) * 4096
                          + (R & 31) * 128 + ((G ^ (R & 7)) * 16));
        short8 vv = *(const short8*)src;
        *(short8*)&out[((long)(b * N_ + q0 + R)) * INNER_ + hd * DH_ + G * 8] = vv;
    }
}

extern "C" void kernel_launch(void* const* d_in, const int* in_sizes, int n_in,
                              void* d_out, int out_size, void* d_ws, size_t ws_size,
                              hipStream_t stream) {
    const void* x    = d_in[0];
    const void* Wqkv = d_in[1];
    const void* Wout = d_in[2];
    const void* bout = d_in[3];
    const void* temp = d_in[4];

    char* base = (char*)d_ws;
    int*   flag    = (int*)base;
    float* temp_f  = (float*)(base + 16);
    float* bias_f  = (float*)(base + 32);
    u16* xb      = (u16*)(base + 8192);
    u16* Wqkv_t  = xb + (long)M_ * D_;
    u16* Wout_t  = Wqkv_t + 3072 * 1024;
    u16* q_ws    = Wout_t + 1024 * 1024;
    u16* k_ws    = q_ws + (long)B_ * H_ * N_ * DH_;
    u16* vt_ws   = k_ws + (long)B_ * H_ * N_ * DH_;
    u16* attn_out = vt_ws + (long)B_ * H_ * N_ * DH_;
    u16* v_nat   = attn_out;  // alias: dead until attn_kernel writes it

    dim3 blk(256);
    detect_dtype<<<1, blk, 0, stream>>>((const u16*)x, flag);
    convert_x<<<dim3(M_ * D_ / (256 * 8)), blk, 0, stream>>>(x, xb, M_ * D_, flag);
    prep_misc<<<1, blk, 0, stream>>>(bout, temp, bias_f, temp_f, flag);
    transpose_cvt<<<dim3(3 * INNER_ / 32, D_ / 32), blk, 0, stream>>>(
        Wqkv, Wqkv_t, D_, 3 * INNER_, flag);
    transpose_cvt<<<dim3(D_ / 32, INNER_ / 32), blk, 0, stream>>>(
        Wout, Wout_t, INNER_, D_, flag);
    gemm_bt<0><<<dim3(M_ / 128, 3 * INNER_ / 128), blk, 0, stream>>>(
        xb, Wqkv_t, M_, 3 * INNER_, D_, q_ws, k_ws, v_nat, nullptr, nullptr,
        flag, temp_f);
    transpose_v<<<dim3(DH_ / 32, N_ / 32, B_ * H_), blk, 0, stream>>>(
        v_nat, vt_ws);
    attn_kernel<<<dim3(N_ / 256, B_ * H_), blk, 0, stream>>>(
        q_ws, k_ws, vt_ws, attn_out);
    gemm_bt<1><<<dim3(M_ / 128, D_ / 128), blk, 0, stream>>>(
        attn_out, Wout_t, M_, D_, INNER_, nullptr, nullptr, nullptr, d_out,
        bias_f, flag, temp_f);
}